// Round 1
// 2637.327 us; speedup vs baseline: 1.1188x; 1.1188x over previous
//
#include <hip/hip_runtime.h>

typedef __attribute__((ext_vector_type(8))) short short8;
typedef __attribute__((ext_vector_type(4))) float floatx4;

#define SXc 179
#define SYc 15
#define SPc 2685
#define WCH 26
#define CHWc 69810
#define N1c 2808
#define KPADc 69824L

__device__ __forceinline__ float geluf(float x){
  return 0.5f*x*(1.f + erff(x*0.7071067811865475f));
}
__device__ __forceinline__ unsigned short f2bfu(float f){
  unsigned int u = __float_as_uint(f);
  u = (u + 0x7fffu + ((u>>16)&1u)) >> 16;
  return (unsigned short)u;
}

__global__ void k_zero(float* p, int n){
  int i = blockIdx.x*256 + threadIdx.x;
  if (i < n) p[i] = 0.f;
}

// h[b,w,x,y] = u0*pw[w,0] + gx*pw[w,1] + gy*pw[w,2] + pb[w]
__global__ __launch_bounds__(256) void k_embed(const float* __restrict__ xin,
    const float* __restrict__ pw, const float* __restrict__ pb, float* __restrict__ Hg){
  int idx = blockIdx.x*256 + threadIdx.x;           // < 256*69810
  int b = idx / CHWc; int r = idx - b*CHWc;
  int c = r / SPc;    int p = r - c*SPc;
  int x = p / 15;     int y = p - x*15;
  float u0 = xin[(b*SXc + x)*16 + y];
  float gx = x*(1.f/178.f), gy = y*(1.f/14.f);
  Hg[idx] = u0*pw[c*3] + gx*pw[c*3+1] + gy*pw[c*3+2] + pb[c];
}

// per (b,c): instance-norm then truncated forward DFT -> F[(b*98+pos)*26+c] (complex)
__global__ __launch_bounds__(256) void k_fwd_dft(const float* __restrict__ Hg, float* __restrict__ Fg){
  __shared__ float sh[SPc];
  __shared__ float2 fy[SXc*7];
  __shared__ float2 part[392];
  __shared__ float2 t179[SXc];
  __shared__ float2 t15[SYc];
  __shared__ float red[8];
  const int tid = threadIdx.x;
  const int bc = blockIdx.x;
  const float* hp = Hg + (size_t)bc*SPc;
  for (int j = tid; j < SXc; j += 256){ float s,c; sincosf(6.283185307179586f*j*(1.f/179.f), &s, &c); t179[j] = make_float2(c,s); }
  for (int j = tid; j < SYc; j += 256){ float s,c; sincosf(6.283185307179586f*j*(1.f/15.f), &s, &c); t15[j] = make_float2(c,s); }
  float s1 = 0.f, s2 = 0.f;
  for (int i = tid; i < SPc; i += 256){ float v = hp[i]; sh[i] = v; s1 += v; s2 += v*v; }
  #pragma unroll
  for (int off=32; off>0; off>>=1){ s1 += __shfl_down(s1,off); s2 += __shfl_down(s2,off); }
  if ((tid&63)==0){ red[tid>>6] = s1; red[4+(tid>>6)] = s2; }
  __syncthreads();
  s1 = red[0]+red[1]+red[2]+red[3];
  s2 = red[4]+red[5]+red[6]+red[7];
  const float mean = s1*(1.f/SPc);
  const float inv = rsqrtf(s2*(1.f/SPc) - mean*mean + 1e-5f);
  for (int i = tid; i < SPc; i += 256) sh[i] = (sh[i]-mean)*inv;
  __syncthreads();
  // stage 1: y-DFT  fy[x*7+ky] = sum_y sh[x,y] * e^{-2pi i ky y/15}
  for (int t = tid; t < SXc*7; t += 256){
    int x = t/7, ky = t - x*7;
    float re=0.f, im=0.f;
    const float* hb = sh + x*15;
    for (int y=0;y<15;y++){
      float v = hb[y];
      float2 w = t15[(ky*y)%15];
      re = fmaf(v,  w.x, re);
      im = fmaf(-v, w.y, im);
    }
    fy[t] = make_float2(re, im);
  }
  __syncthreads();
  // stage 2: x-DFT at kx in {0..6, 172..178}
  for (int t = tid; t < 392; t += 256){
    int o = t>>2, q = t&3;
    int kxi = o/7, ky = o - kxi*7;
    int kx = (kxi<7) ? kxi : kxi+165;
    int x0 = q*45, x1e = (x0+45 < SXc) ? x0+45 : SXc;
    float re=0.f, im=0.f;
    for (int x=x0;x<x1e;x++){
      float2 f = fy[x*7+ky];
      float2 w = t179[(kx*x)%179];
      re += f.x*w.x + f.y*w.y;     // (fr+ifi)(c-is)
      im += f.y*w.x - f.x*w.y;
    }
    part[t] = make_float2(re, im);
  }
  __syncthreads();
  const int b = bc/WCH, ch = bc - (bc/WCH)*WCH;
  for (int t = tid; t < 98; t += 256){
    float2 a0=part[4*t], a1=part[4*t+1], a2=part[4*t+2], a3=part[4*t+3];
    float* outp = Fg + (((size_t)b*98 + t)*WCH + ch)*2;
    outp[0] = a0.x+a1.x+a2.x+a3.x;
    outp[1] = a0.y+a1.y+a2.y+a3.y;
  }
}

// per b: complex channel mix. F[(b*98+pos)*26+i] -> F2[((b*26+o)*98)+pos]
__global__ __launch_bounds__(256) void k_mix(const float* __restrict__ Fg, float* __restrict__ F2g,
                      const float* __restrict__ w1, const float* __restrict__ w2){
  const int b = blockIdx.x, tid = threadIdx.x;
  __shared__ float2 fin[98*WCH];
  const float2* src = (const float2*)(Fg + (size_t)b*98*WCH*2);
  for (int i = tid; i < 98*WCH; i += 256) fin[i] = src[i];
  __syncthreads();
  for (int t = tid; t < 98*WCH; t += 256){
    int pos = t/WCH, o = t - pos*WCH;
    int kxi = pos/7, ky = pos - kxi*7;
    const float* wsrc = (kxi<7) ? w1 : w2;
    int mx = (kxi<7) ? kxi : kxi-7;
    float re=0.f, im=0.f;
    const float2* fp = fin + pos*WCH;
    for (int i=0;i<WCH;i++){
      float2 f = fp[i];
      const float* wp = wsrc + (((i*WCH+o)*7+mx)*7+ky)*2;
      float wr = wp[0], wi = wp[1];
      re += f.x*wr - f.y*wi;
      im += f.x*wi + f.y*wr;
    }
    float2* dst = (float2*)(F2g + (((size_t)b*WCH + o)*98 + pos)*2);
    *dst = make_float2(re, im);
  }
}

// per (b,c): truncated inverse DFT + instance-norm -> T[b,c,:,:]
__global__ __launch_bounds__(256) void k_inv_dft(const float* __restrict__ F2g, float* __restrict__ Tg){
  __shared__ float2 fin[98];
  __shared__ float2 tmp[SXc*7];
  __shared__ float outv[SPc];
  __shared__ float2 t179[SXc];
  __shared__ float2 t15[SYc];
  __shared__ float red[8];
  const int tid = threadIdx.x;
  const int bc = blockIdx.x;
  for (int j = tid; j < SXc; j += 256){ float s,c; sincosf(6.283185307179586f*j*(1.f/179.f), &s, &c); t179[j] = make_float2(c,s); }
  for (int j = tid; j < SYc; j += 256){ float s,c; sincosf(6.283185307179586f*j*(1.f/15.f), &s, &c); t15[j] = make_float2(c,s); }
  const float2* src = (const float2*)(F2g + (size_t)bc*98*2);
  for (int j = tid; j < 98; j += 256) fin[j] = src[j];
  __syncthreads();
  // stage 1: tmp[x*7+ky] = sum_kxi fin[kxi*7+ky] * e^{+2pi i kx x/179}
  for (int t = tid; t < SXc*7; t += 256){
    int x = t/7, ky = t - (t/7)*7;
    float re=0.f, im=0.f;
    #pragma unroll
    for (int kxi=0;kxi<14;kxi++){
      float2 f = fin[kxi*7+ky];
      int kx = (kxi<7) ? kxi : kxi+165;
      float2 w = t179[(kx*x)%179];
      re += f.x*w.x - f.y*w.y;     // (fr+ifi)(c+is)
      im += f.x*w.y + f.y*w.x;
    }
    tmp[t] = make_float2(re, im);
  }
  __syncthreads();
  float s1=0.f, s2=0.f;
  for (int p = tid; p < SPc; p += 256){
    int x = p/15, y = p - x*15;
    const float2* tp = tmp + x*7;
    float v = tp[0].x;
    #pragma unroll
    for (int ky=1;ky<7;ky++){
      float2 f = tp[ky];
      float2 w = t15[(ky*y)%15];
      v += 2.f*(f.x*w.x - f.y*w.y);
    }
    v *= (1.f/2685.f);
    outv[p] = v; s1 += v; s2 += v*v;
  }
  #pragma unroll
  for (int off=32; off>0; off>>=1){ s1 += __shfl_down(s1,off); s2 += __shfl_down(s2,off); }
  if ((tid&63)==0){ red[tid>>6] = s1; red[4+(tid>>6)] = s2; }
  __syncthreads();
  s1 = red[0]+red[1]+red[2]+red[3];
  s2 = red[4]+red[5]+red[6]+red[7];
  const float mean = s1*(1.f/SPc);
  const float inv = rsqrtf(s2*(1.f/SPc) - mean*mean + 1e-5f);
  float* outp = Tg + (size_t)bc*SPc;
  for (int p = tid; p < SPc; p += 256) outp[p] = (outv[p]-mean)*inv;
}

// per (b,p): h <- gelu( mlp(t) + c1(h) ), in place on H
__global__ __launch_bounds__(256) void k_mlp_res(const float* __restrict__ Tg, float* __restrict__ Hg,
     const float* __restrict__ w1, const float* __restrict__ b1,
     const float* __restrict__ w2, const float* __restrict__ b2,
     const float* __restrict__ ww, const float* __restrict__ wb){
  const int idx = blockIdx.x*256 + threadIdx.x;    // < 256*2685
  const int b = idx / SPc, p = idx - (idx/SPc)*SPc;
  const float* tp = Tg + (size_t)b*CHWc + p;
  float* hp = Hg + (size_t)b*CHWc + p;
  float tv[WCH], hv[WCH], m1[WCH];
  #pragma unroll
  for (int i=0;i<WCH;i++) tv[i] = tp[i*SPc];
  #pragma unroll
  for (int i=0;i<WCH;i++) hv[i] = hp[i*SPc];
  #pragma unroll
  for (int o=0;o<WCH;o++){
    float a = b1[o];
    #pragma unroll
    for (int i=0;i<WCH;i++) a = fmaf(tv[i], w1[o*WCH+i], a);
    m1[o] = geluf(a);
  }
  #pragma unroll
  for (int o=0;o<WCH;o++){
    float a = b2[o] + wb[o];
    #pragma unroll
    for (int i=0;i<WCH;i++) a = fmaf(m1[i], w2[o*WCH+i], a);
    #pragma unroll
    for (int i=0;i<WCH;i++) a = fmaf(hv[i], ww[o*WCH+i], a);
    hp[o*SPc] = geluf(a);
  }
}

// spatial attention: 3x3 conv + relu, summed over spatial into S[b,o]
__global__ __launch_bounds__(256) void k_conv_att(const float* __restrict__ Hg, float* __restrict__ Sg,
                           const float* __restrict__ cw, const float* __restrict__ cb){
  const int b = blockIdx.y;
  const int p = blockIdx.x*256 + threadIdx.x;
  const bool valid = (p < SPc);
  const int x = p/15, y = p - (p/15)*15;
  float acc[WCH];
  #pragma unroll
  for (int o=0;o<WCH;o++) acc[o] = 0.f;
  const float* hb = Hg + (size_t)b*CHWc;
  for (int i=0;i<WCH;i++){
    const float* hc = hb + i*SPc;
    #pragma unroll
    for (int dx=0;dx<3;dx++){
      const int xx = x + dx - 1;
      #pragma unroll
      for (int dy=0;dy<3;dy++){
        const int yy = y + dy - 1;
        float v = 0.f;
        if (valid && xx>=0 && xx<SXc && yy>=0 && yy<SYc) v = hc[xx*15+yy];
        #pragma unroll
        for (int o=0;o<WCH;o++) acc[o] = fmaf(v, cw[((o*WCH+i)*3+dx)*3+dy], acc[o]);
      }
    }
  }
  #pragma unroll
  for (int o=0;o<WCH;o++){
    float r = valid ? fmaxf(acc[o] + cb[o], 0.f) : 0.f;
    #pragma unroll
    for (int off=32; off>0; off>>=1) r += __shfl_down(r, off);
    if ((threadIdx.x&63)==0) atomicAdd(&Sg[b*WCH+o], r);
  }
}

__global__ void k_attfc(const float* __restrict__ Sg, const float* __restrict__ fw,
                        const float* __restrict__ fb, float* __restrict__ Ag){
  int b = threadIdx.x;
  float a = fb[0];
  for (int o=0;o<WCH;o++) a = fmaf(Sg[b*WCH+o]*(1.f/2685.f), fw[o], a);
  Ag[b] = 1.f/(1.f + expf(-a));
}

// bf16 copy of H (K padded to 69824 with zeros); attention scale folded in later
__global__ __launch_bounds__(256) void k_prepA(const float* __restrict__ Hg, unsigned short* __restrict__ Ab){
  int idx = blockIdx.x*256 + threadIdx.x;          // < 256*69824
  int b = idx / (int)KPADc; int j = idx - b*(int)KPADc;
  float v = (j < CHWc) ? Hg[(size_t)b*CHWc + j] : 0.f;
  Ab[idx] = f2bfu(v);
}

// C[256 x 2808] += A[256 x K] * W[2808 x K]^T, bf16 MFMA, split-K atomics
// Tile: M=256 (full batch), N=128, BK=32; 8 waves (4M x 2N); double-buffered LDS
// 2-phase pipeline: A via global_load_lds(16B), W reg-staged fp32->bf16.
// XOR swizzle slot^=(row&3): pre-swizzled GLOBAL source + swizzled ds_read (LDS dest linear).
// grid (22 nblk, 23 kslices)
__global__ __launch_bounds__(512, 4) void k_gemm1(const unsigned short* __restrict__ Ab,
                        const float* __restrict__ Wg, float* __restrict__ Cg){
  __shared__ __align__(16) unsigned short As[2][256*32];   // 2 x 16 KB
  __shared__ __align__(16) unsigned short Bs[2][128*32];   // 2 x 8 KB
  const int tid = threadIdx.x;
  const int bn = blockIdx.x, bs = blockIdx.y;
  const int itStart = bs*95;
  const int itEnd = (itStart+95 < 2182) ? itStart+95 : 2182;
  const int wave = tid>>6, lane = tid&63;
  const int wm = (wave>>1)*64;                 // 0,64,128,192
  const int wn = (wave&1)*64;                  // 0,64
  const int r16 = lane&15, quad = lane>>4;
  const int swz = r16&3;                       // read-side slot XOR

  // W staging geometry: 4 threads/row, 8 floats each
  const int wrow = tid>>2, wseg0 = tid&3;
  const int wsegG = wseg0 ^ (wrow&3);          // global k-segment this thread fetches
  const int gn_w = bn*128 + wrow;
  const bool wvalid = (gn_w < N1c);
  const float* wbase = Wg + (size_t)gn_w*CHWc;

  floatx4 acc[4][4];
  #pragma unroll
  for (int i=0;i<4;i++)
    #pragma unroll
    for (int j=0;j<4;j++){ acc[i][j].x=0.f; acc[i][j].y=0.f; acc[i][j].z=0.f; acc[i][j].w=0.f; }

  float wv0,wv1,wv2,wv3,wv4,wv5,wv6,wv7;

  auto stageA = [&](int buf, int it){
    const int k0 = it*32;
    #pragma unroll
    for (int i=0;i<2;i++){
      const int chunk = (i*8 + wave)*64 + lane;
      const int row = chunk>>2, q = chunk&3;
      const int qs = q ^ (row&3);              // pre-swizzled global segment
      const unsigned short* gp = Ab + (size_t)row*KPADc + (k0 + qs*8);
      unsigned short* lp = &As[buf][(i*8 + wave)*512];   // wave-uniform base, lane*16B appended by HW
      __builtin_amdgcn_global_load_lds((__attribute__((address_space(1))) void*)gp,
                                       (__attribute__((address_space(3))) void*)lp, 16, 0, 0);
    }
  };
  auto loadW = [&](int it){
    const int kk = it*32 + wsegG*8;
    if (wvalid && kk + 8 <= CHWc){
      const float2* p = (const float2*)(wbase + kk);     // rows are 8B aligned
      float2 a = p[0], b2_ = p[1], c = p[2], d = p[3];
      wv0=a.x; wv1=a.y; wv2=b2_.x; wv3=b2_.y; wv4=c.x; wv5=c.y; wv6=d.x; wv7=d.y;
    } else {
      wv0 = (wvalid && kk   < CHWc) ? wbase[kk]   : 0.f;
      wv1 = (wvalid && kk+1 < CHWc) ? wbase[kk+1] : 0.f;
      wv2 = (wvalid && kk+2 < CHWc) ? wbase[kk+2] : 0.f;
      wv3 = (wvalid && kk+3 < CHWc) ? wbase[kk+3] : 0.f;
      wv4 = (wvalid && kk+4 < CHWc) ? wbase[kk+4] : 0.f;
      wv5 = (wvalid && kk+5 < CHWc) ? wbase[kk+5] : 0.f;
      wv6 = (wvalid && kk+6 < CHWc) ? wbase[kk+6] : 0.f;
      wv7 = (wvalid && kk+7 < CHWc) ? wbase[kk+7] : 0.f;
    }
  };
  auto writeW = [&](int buf){
    short8 pk;
    pk[0]=(short)f2bfu(wv0); pk[1]=(short)f2bfu(wv1);
    pk[2]=(short)f2bfu(wv2); pk[3]=(short)f2bfu(wv3);
    pk[4]=(short)f2bfu(wv4); pk[5]=(short)f2bfu(wv5);
    pk[6]=(short)f2bfu(wv6); pk[7]=(short)f2bfu(wv7);
    *(short8*)(&Bs[buf][tid*8]) = pk;          // linear slot wseg0, holds global seg wseg0^(row&3)
  };

  // prologue: tile itStart -> buffer 0
  loadW(itStart);
  stageA(0, itStart);
  writeW(0);
  __syncthreads();

  int cur = 0;
  for (int it = itStart; it < itEnd; ++it){
    const int nxt = cur^1;
    const bool more = (it+1 < itEnd);
    if (more){
      stageA(nxt, it+1);      // issue async global->LDS early
      loadW(it+1);            // issue W global loads early (consumed after MFMAs)
    }
    short8 af[4], bf[4];
    #pragma unroll
    for (int t=0;t<4;t++){
      af[t] = *(const short8*)(&As[cur][(wm + t*16 + r16)*32 + ((quad ^ swz)*8)]);
      bf[t] = *(const short8*)(&Bs[cur][(wn + t*16 + r16)*32 + ((quad ^ swz)*8)]);
    }
    #pragma unroll
    for (int tm=0;tm<4;tm++)
      #pragma unroll
      for (int tn=0;tn<4;tn++)
        acc[tm][tn] = __builtin_amdgcn_mfma_f32_16x16x32_bf16(af[tm], bf[tn], acc[tm][tn], 0, 0, 0);
    if (more) writeW(nxt);
    __syncthreads();          // drains glds (vmcnt) + ds_writes (lgkm); tile nxt ready
    cur = nxt;
  }

  #pragma unroll
  for (int tm=0;tm<4;tm++){
    #pragma unroll
    for (int tn=0;tn<4;tn++){
      const int gn = bn*128 + wn + tn*16 + r16;
      if (gn < N1c){
        #pragma unroll
        for (int r=0;r<4;r++){
          const int gm = wm + tm*16 + quad*4 + r;
          atomicAdd(&Cg[(size_t)gm*N1c + gn], acc[tm][tn][r]);
        }
      }
    }
  }
}

// x1[b,m] = b2[m] + sum_n leaky(a[b]*gemm[b,n] + b1[n]) * w2[m,n]
__global__ __launch_bounds__(128) void k_x1(const float* __restrict__ x1pre, const float* __restrict__ Ag,
                     const float* __restrict__ b1, const float* __restrict__ w2,
                     const float* __restrict__ b2, float* __restrict__ X1){
  const int b = blockIdx.x;
  const int tid = threadIdx.x;
  __shared__ float lr[N1c];
  const float ab = Ag[b];
  for (int n = tid; n < N1c; n += 128){
    float v = fmaf(ab, x1pre[(size_t)b*N1c + n], b1[n]);
    lr[n] = v > 0.f ? v : 0.01f*v;
  }
  __syncthreads();
  float acc = b2[tid];
  const floatx4* wr = (const floatx4*)(w2 + (size_t)tid*N1c);
  const floatx4* l4 = (const floatx4*)lr;
  for (int n=0;n<N1c/4;n++){
    floatx4 w = wr[n], l = l4[n];
    acc += l.x*w.x + l.y*w.y + l.z*w.z + l.w*w.w;
  }
  X1[b*128 + tid] = acc;
}

__global__ void k_final(const float* __restrict__ X1, const float* __restrict__ xin,
                        const float* __restrict__ rw, const float* __restrict__ rb,
                        float* __restrict__ outp){
  int b = threadIdx.x;
  float acc = rb[0];
  for (int k=0;k<128;k++){
    float x1v = X1[b*128+k];
    float x0v = (xin[(b*SXc + k)*16 + 15] - 400.f)*0.01f;
    acc = fmaf(x1v, rw[2*k], acc);
    acc = fmaf(x0v, rw[2*k+1], acc);
  }
  outp[b] = acc;
}

extern "C" void kernel_launch(void* const* d_in, const int* in_sizes, int n_in,
                              void* d_out, int out_size, void* d_ws, size_t ws_size,
                              hipStream_t stream) {
  const float* xin  = (const float*)d_in[0];
  const float* p_w  = (const float*)d_in[1];
  const float* p_b  = (const float*)d_in[2];
  const float* sc_w1[2] = {(const float*)d_in[3], (const float*)d_in[5]};
  const float* sc_w2[2] = {(const float*)d_in[4], (const float*)d_in[6]};
  const float* m_w1[2]  = {(const float*)d_in[7],  (const float*)d_in[11]};
  const float* m_b1[2]  = {(const float*)d_in[8],  (const float*)d_in[12]};
  const float* m_w2[2]  = {(const float*)d_in[9],  (const float*)d_in[13]};
  const float* m_b2[2]  = {(const float*)d_in[10], (const float*)d_in[14]};
  const float* w_w[2]   = {(const float*)d_in[15], (const float*)d_in[17]};
  const float* w_b[2]   = {(const float*)d_in[16], (const float*)d_in[18]};
  const float* sa_cw = (const float*)d_in[19];
  const float* sa_cb = (const float*)d_in[20];
  const float* sa_fw = (const float*)d_in[21];
  const float* sa_fb = (const float*)d_in[22];
  const float* o1w1  = (const float*)d_in[23];
  const float* o1b1  = (const float*)d_in[24];
  const float* o1w2  = (const float*)d_in[25];
  const float* o1b2  = (const float*)d_in[26];
  const float* rw    = (const float*)d_in[27];
  const float* rb    = (const float*)d_in[28];

  char* ws = (char*)d_ws;
  float* Hb  = (float*)(ws + 0);                    // 71,485,440 B
  float* Tb  = (float*)(ws + 71485440);             // 71,485,440 B
  float* Fb  = (float*)(ws + 142970880);            // 5,218,304 B
  float* F2b = (float*)(ws + 148189184);            // 5,218,304 B  (total 153,407,488)
  // overlays (lifetimes disjoint):
  unsigned short* Ab = (unsigned short*)(ws + 71485440);   // over Tb (dead after block 2)
  float* x1pre = (float*)(ws + 142970880);                 // over Fb
  float* X1b   = (float*)(ws + 142970880 + 2875392);
  float* Sb    = (float*)(ws + 142970880 + 2875392 + 131072);
  float* Aat   = (float*)(ws + 142970880 + 2875392 + 131072 + 26624);

  k_embed<<<CHWc, 256, 0, stream>>>(xin, p_w, p_b, Hb);

  for (int blk = 0; blk < 2; ++blk){
    k_fwd_dft<<<256*WCH, 256, 0, stream>>>(Hb, Fb);
    k_mix<<<256, 256, 0, stream>>>(Fb, F2b, sc_w1[blk], sc_w2[blk]);
    k_inv_dft<<<256*WCH, 256, 0, stream>>>(F2b, Tb);
    k_mlp_res<<<SPc, 256, 0, stream>>>(Tb, Hb, m_w1[blk], m_b1[blk], m_w2[blk], m_b2[blk], w_w[blk], w_b[blk]);
  }

  k_zero<<<26, 256, 0, stream>>>(Sb, 256*WCH);
  k_conv_att<<<dim3(11, 256), 256, 0, stream>>>(Hb, Sb, sa_cw, sa_cb);
  k_attfc<<<1, 256, 0, stream>>>(Sb, sa_fw, sa_fb, Aat);

  k_prepA<<<(int)KPADc, 256, 0, stream>>>(Hb, Ab);
  k_zero<<<N1c, 256, 0, stream>>>(x1pre, 256*N1c);
  k_gemm1<<<dim3(22, 23), 512, 0, stream>>>(Ab, o1w1, x1pre);
  k_x1<<<256, 128, 0, stream>>>(x1pre, Aat, o1b1, o1w2, o1b2, X1b);
  k_final<<<1, 256, 0, stream>>>(X1b, xin, rw, rb, (float*)d_out);
}